// Round 10
// baseline (4236.705 us; speedup 1.0000x reference)
//
#include <hip/hip_runtime.h>

#define NC 512
#define WSZ 64
#define RH 4
#define BA 16
#define TS 32
#define IFSZ 471
#define EPSC 1e-8f

// ---------- helpers ----------
__device__ __forceinline__ float wave_sum(float v) {
#pragma unroll
  for (int m = 32; m >= 1; m >>= 1) v += __shfl_xor(v, m, 64);
  return v;
}
__device__ __forceinline__ float wave_max(float v) {
#pragma unroll
  for (int m = 32; m >= 1; m >>= 1) v = fmaxf(v, __shfl_xor(v, m, 64));
  return v;
}
__device__ __forceinline__ float softplus_f(float x) {
  return fmaxf(x, 0.f) + log1pf(expf(-fabsf(x)));
}
__device__ __forceinline__ float sigmoid_f(float x) {
  return 1.f / (1.f + expf(-x));
}

// ---------- interface GEMM + activations (once, parallel) ----------
__global__ __launch_bounds__(512) void iface_kernel(
    const float* __restrict__ ctrl, const float* __restrict__ W,
    const float* __restrict__ bif, float* __restrict__ iface) {
  int bt = blockIdx.x;
  int tid = threadIdx.x;
  __shared__ float s_ctrl[512];
  __shared__ float s_v[IFSZ];
  s_ctrl[tid] = ctrl[(size_t)bt * 512 + tid];
  __syncthreads();
  if (tid < IFSZ) {
    float acc = bif[tid];
#pragma unroll 8
    for (int k = 0; k < 512; k++) acc = fmaf(s_ctrl[k], W[(size_t)k * IFSZ + tid], acc);
    s_v[tid] = acc;
  }
  __syncthreads();
  if (tid < IFSZ) {
    float v = s_v[tid];
    float o;
    if (tid < 256) o = v;
    else if (tid < 260) o = softplus_f(v);
    else if (tid < 324) o = v;
    else if (tid < 325) o = softplus_f(v);
    else if (tid < 389) o = sigmoid_f(v);
    else if (tid < 453) o = v;
    else if (tid < 459) o = sigmoid_f(v);
    else {
      int g = (tid - 459) / 3;
      int base = 459 + g * 3;
      float a = s_v[base], b = s_v[base + 1], c = s_v[base + 2];
      float mx = fmaxf(a, fmaxf(b, c));
      float ea = expf(a - mx), eb = expf(b - mx), ec = expf(c - mx);
      o = expf(v - mx) / (ea + eb + ec);
    }
    iface[(size_t)bt * IFSZ + tid] = o;
  }
}

// ---------- mega kernel: ONE BLOCK PER BATCH, whole T loop, zero cross-block sync ----------
// All reductions are block-local (N=512 = blockDim). Link streams through this
// CU's L2 (1 MB/batch, never flushed — single launch). Link is provably zero
// until t=1, so it is never read before being written (poison-safe, no init).
__global__ __launch_bounds__(512) void dnc_mega(
    const float* __restrict__ iface, float* __restrict__ mem,
    float* __restrict__ link, float* __restrict__ out) {
  const int b = blockIdx.x;
  const int tid = threadIdx.x, lane = tid & 63, wid = tid >> 6;
  const int n = tid;
  const size_t bn = (size_t)b * NC;
  float* lbase = link + (size_t)b * NC * NC;
  float* mb = mem + bn * WSZ;

  __shared__ float s_keys[5][64], s_e[64], s_v[64];
  __shared__ __align__(16) float s_u[NC];
  __shared__ float s_rw4[4][NC];
  __shared__ float s_ww[NC], s_prec[NC];
  __shared__ float s_fwd[4][NC];   // fwd(t) = link(t) . rw(t-1)
  __shared__ float s_bp[4][NC];    // bwd(t) = link(t)^T . rw(t-1)
  __shared__ float s_treeR[4][NC]; // bwd tree tmp; also read-words partials
  __shared__ float s_redA[8][5], s_redB[8][5], s_red[8];

  for (int t = 0; t <= TS; ++t) {
    const float* ifcA = iface + ((size_t)b * TS + (t < TS ? t : TS - 1)) * IFSZ;
    const float* ifcB = iface + ((size_t)b * TS + (t > 0 ? t - 1 : 0)) * IFSZ;
    const bool have_w = (t < TS);

    // ---- A: staging ----
    if (t > 0 && wid < 4) {                 // read keys of step t-1
      float k = ifcB[wid * 64 + lane];
      float ss = wave_sum(k * k);
      s_keys[wid][lane] = k * rsqrtf(ss + EPSC);
    } else if (t > 0 && have_w && wid == 4) {  // write key of step t
      float k = ifcA[260 + lane];
      float ss = wave_sum(k * k);
      s_keys[4][lane] = k * rsqrtf(ss + EPSC);
    } else if (have_w && wid == 5) {
      s_e[lane] = ifcA[325 + lane];
    } else if (have_w && wid == 6) {
      s_v[lane] = ifcA[389 + lane];
    }
    if (t == 0) { s_u[n] = 0.f; s_prec[n] = 0.f; }
    __syncthreads();  // S1

    // ---- phase B: rw(t-1) (and wcw for step t) ----
    float rwreg[4], wcw;
    if (t > 0) {
      const float4* mrow = (const float4*)(mb + (size_t)n * WSZ);
      float msum = 0.f, d0 = 0.f, d1 = 0.f, d2 = 0.f, d3 = 0.f, dw = 0.f;
#pragma unroll
      for (int i = 0; i < 16; i++) {
        float4 mm = mrow[i];
        msum = fmaf(mm.x, mm.x, fmaf(mm.y, mm.y, fmaf(mm.z, mm.z, fmaf(mm.w, mm.w, msum))));
        d0 = fmaf(mm.x, s_keys[0][4 * i], fmaf(mm.y, s_keys[0][4 * i + 1],
             fmaf(mm.z, s_keys[0][4 * i + 2], fmaf(mm.w, s_keys[0][4 * i + 3], d0))));
        d1 = fmaf(mm.x, s_keys[1][4 * i], fmaf(mm.y, s_keys[1][4 * i + 1],
             fmaf(mm.z, s_keys[1][4 * i + 2], fmaf(mm.w, s_keys[1][4 * i + 3], d1))));
        d2 = fmaf(mm.x, s_keys[2][4 * i], fmaf(mm.y, s_keys[2][4 * i + 1],
             fmaf(mm.z, s_keys[2][4 * i + 2], fmaf(mm.w, s_keys[2][4 * i + 3], d2))));
        d3 = fmaf(mm.x, s_keys[3][4 * i], fmaf(mm.y, s_keys[3][4 * i + 1],
             fmaf(mm.z, s_keys[3][4 * i + 2], fmaf(mm.w, s_keys[3][4 * i + 3], d3))));
        if (have_w)
          dw = fmaf(mm.x, s_keys[4][4 * i], fmaf(mm.y, s_keys[4][4 * i + 1],
               fmaf(mm.z, s_keys[4][4 * i + 2], fmaf(mm.w, s_keys[4][4 * i + 3], dw))));
      }
      float minv = rsqrtf(msum + EPSC);
      float sim[5];
      sim[0] = d0 * minv * ifcB[256];
      sim[1] = d1 * minv * ifcB[257];
      sim[2] = d2 * minv * ifcB[258];
      sim[3] = d3 * minv * ifcB[259];
      sim[4] = have_w ? dw * minv * ifcA[324] : 0.f;
#pragma unroll
      for (int i = 0; i < 5; i++) {
        float wm = wave_max(sim[i]);
        if (lane == 0) s_redA[wid][i] = wm;
      }
      __syncthreads();  // S2
      float ex[5];
#pragma unroll
      for (int i = 0; i < 5; i++) {
        float mx = s_redA[0][i];
#pragma unroll
        for (int w = 1; w < 8; w++) mx = fmaxf(mx, s_redA[w][i]);
        ex[i] = expf(sim[i] - mx);
        float ws_ = wave_sum(ex[i]);
        if (lane == 0) s_redB[wid][i] = ws_;
      }
      __syncthreads();  // S3
      float den[5];
#pragma unroll
      for (int i = 0; i < 5; i++) {
        float s = 0.f;
#pragma unroll
        for (int w = 0; w < 8; w++) s += s_redB[w][i];
        den[i] = s;
      }
      wcw = have_w ? ex[4] / den[4] : 0.f;
#pragma unroll
      for (int r = 0; r < 4; r++) {
        float rcw = ex[r] / den[r];
        float m0 = ifcB[459 + r * 3], m1 = ifcB[459 + r * 3 + 1], m2 = ifcB[459 + r * 3 + 2];
        rwreg[r] = fmaf(m0, s_bp[r][n], fmaf(m1, rcw, m2 * s_fwd[r][n]));
      }
    } else {
#pragma unroll
      for (int r = 0; r < 4; r++) rwreg[r] = 1.f / NC;
      wcw = 1.f / NC;
    }
#pragma unroll
    for (int r = 0; r < 4; r++) s_rw4[r][n] = rwreg[r];

    // ---- D: write weights + usage prep (step t) ----
    float wwn = 0.f, unew = 0.f, pr_n = 0.f;
    if (have_w) {
      float un = s_u[n];
      pr_n = s_prec[n];
      float pp = 1.f;
#pragma unroll 4
      for (int j4 = 0; j4 < NC / 4; ++j4) {
        float4 u4 = *(const float4*)&s_u[j4 * 4];
        int ja = j4 * 4;
        pp *= ((u4.x < un) || (u4.x == un && (ja + 0) < n)) ? u4.x : 1.f;
        pp *= ((u4.y < un) || (u4.y == un && (ja + 1) < n)) ? u4.y : 1.f;
        pp *= ((u4.z < un) || (u4.z == un && (ja + 2) < n)) ? u4.z : 1.f;
        pp *= ((u4.w < un) || (u4.w == un && (ja + 3) < n)) ? u4.w : 1.f;
      }
      float allocv = (1.f - un) * pp;
      float ag = ifcA[457], wg = ifcA[458];
      wwn = wg * (ag * allocv + (1.f - ag) * wcw);
      s_ww[n] = wwn;
      float u = un + wwn - un * wwn;
      float psi = 1.f;
#pragma unroll
      for (int r = 0; r < 4; r++) psi *= (1.f - ifcA[453 + r] * rwreg[r]);
      unew = u * psi;
    }
    __syncthreads();  // S4: s_rw4, s_ww live

    // ---- G: read words -> out(t-1) ----
    if (t > 0) {
      float* s_part = &s_treeR[0][0];  // [8][4][64]
      float a0 = 0.f, a1 = 0.f, a2 = 0.f, a3 = 0.f;
#pragma unroll 8
      for (int k = 0; k < 64; k++) {
        int row = wid * 64 + k;
        float m = mb[(size_t)row * WSZ + lane];
        a0 = fmaf(s_rw4[0][row], m, a0);
        a1 = fmaf(s_rw4[1][row], m, a1);
        a2 = fmaf(s_rw4[2][row], m, a2);
        a3 = fmaf(s_rw4[3][row], m, a3);
      }
      s_part[(wid * 4 + 0) * 64 + lane] = a0;
      s_part[(wid * 4 + 1) * 64 + lane] = a1;
      s_part[(wid * 4 + 2) * 64 + lane] = a2;
      s_part[(wid * 4 + 3) * 64 + lane] = a3;
      __syncthreads();  // S6
      if (tid < 256) {
        int r = tid >> 6, w = tid & 63;
        float a = 0.f;
#pragma unroll
        for (int wv = 0; wv < 8; wv++) a += s_part[(wv * 4 + r) * 64 + w];
        out[(((size_t)b * TS + (t - 1)) * RH + r) * WSZ + w] = a;
      }
      __syncthreads();  // S6b: s_part reads done before treeR reuse
    }
    if (t == TS) return;

    // ---- F: usage + prec (values; stores deferred) ----
    s_u[n] = unew;  // safe: pp reads were before S4
    {
      float w_ = wave_sum(wwn);
      if (lane == 0) s_red[wid] = w_;
    }
    __syncthreads();
    float sw = 0.f;
#pragma unroll
    for (int i = 0; i < 8; i++) sw += s_red[i];
    float prec_new = (1.f - sw) * pr_n + wwn;

    // ---- H: link update (streamed via own L2) + fwd + bwd partials ----
    float bc[4][8];
#pragma unroll
    for (int a = 0; a < 4; a++)
#pragma unroll
      for (int c = 0; c < 8; c++) bc[a][c] = 0.f;

#pragma unroll 2
    for (int rr = 0; rr < 64; ++rr) {
      int i = wid * 64 + rr;
      float wsi = s_ww[i];
      float rwi0 = s_rw4[0][i], rwi1 = s_rw4[1][i], rwi2 = s_rw4[2][i], rwi3 = s_rw4[3][i];
      float f0 = 0.f, f1 = 0.f, f2 = 0.f, f3 = 0.f;
      float* lrow = lbase + (size_t)i * NC;
      if (t >= 2) {
#pragma unroll
        for (int jj = 0; jj < 8; ++jj) {
          int j = jj * 64 + lane;
          float l = lrow[j];
          float ln = fmaf(1.f - wsi - s_ww[j], l, wsi * s_prec[j]);
          if (j == i) ln = 0.f;
          lrow[j] = ln;
          f0 = fmaf(ln, s_rw4[0][j], f0);
          f1 = fmaf(ln, s_rw4[1][j], f1);
          f2 = fmaf(ln, s_rw4[2][j], f2);
          f3 = fmaf(ln, s_rw4[3][j], f3);
          bc[0][jj] = fmaf(ln, rwi0, bc[0][jj]);
          bc[1][jj] = fmaf(ln, rwi1, bc[1][jj]);
          bc[2][jj] = fmaf(ln, rwi2, bc[2][jj]);
          bc[3][jj] = fmaf(ln, rwi3, bc[3][jj]);
        }
      } else {  // t==0: prec=0 -> ln=0 (no store). t==1: link_old=0 (no load).
#pragma unroll
        for (int jj = 0; jj < 8; ++jj) {
          int j = jj * 64 + lane;
          float ln = wsi * s_prec[j];
          if (j == i) ln = 0.f;
          if (t == 1) lrow[j] = ln;
          f0 = fmaf(ln, s_rw4[0][j], f0);
          f1 = fmaf(ln, s_rw4[1][j], f1);
          f2 = fmaf(ln, s_rw4[2][j], f2);
          f3 = fmaf(ln, s_rw4[3][j], f3);
          bc[0][jj] = fmaf(ln, rwi0, bc[0][jj]);
          bc[1][jj] = fmaf(ln, rwi1, bc[1][jj]);
          bc[2][jj] = fmaf(ln, rwi2, bc[2][jj]);
          bc[3][jj] = fmaf(ln, rwi3, bc[3][jj]);
        }
      }
      f0 = wave_sum(f0);
      f1 = wave_sum(f1);
      f2 = wave_sum(f2);
      f3 = wave_sum(f3);
      if (lane == 0) {
        s_fwd[0][i] = f0; s_fwd[1][i] = f1; s_fwd[2][i] = f2; s_fwd[3][i] = f3;
      }
    }
    // bwd: per-r 2-round LDS tree into s_bp (deterministic fixed order)
#pragma unroll 1
    for (int r = 0; r < 4; ++r) {
      if (wid >= 4) {
#pragma unroll
        for (int jj = 0; jj < 8; ++jj) s_treeR[wid - 4][jj * 64 + lane] = bc[r][jj];
      }
      __syncthreads();
      if (wid < 4) {
#pragma unroll
        for (int jj = 0; jj < 8; ++jj) s_treeR[wid][jj * 64 + lane] += bc[r][jj];
      }
      __syncthreads();
      s_bp[r][tid] = (s_treeR[0][tid] + s_treeR[1][tid]) +
                     (s_treeR[2][tid] + s_treeR[3][tid]);
      __syncthreads();
    }

    // ---- I: memory erase+write, in place (each element owned by one thread) ----
#pragma unroll 4
    for (int kk = 0; kk < 64; ++kk) {
      int flat = tid + kk * 512;
      int row = flat >> 6, w = flat & 63;
      float mv = (t == 0) ? 0.f : mb[flat];
      mb[flat] = fmaf(mv, 1.f - s_ww[row] * s_e[w], s_ww[row] * s_v[w]);
    }

    // ---- J: commit prec (link loop done reading old s_prec) ----
    s_prec[n] = prec_new;
    __syncthreads();  // S9
  }
}

// ---------- host ----------
extern "C" void kernel_launch(void* const* d_in, const int* in_sizes, int n_in,
                              void* d_out, int out_size, void* d_ws, size_t ws_size,
                              hipStream_t stream) {
  const float* ctrl = (const float*)d_in[0];
  const float* Wif = (const float*)d_in[1];
  const float* bif = (const float*)d_in[2];
  float* out = (float*)d_out;

  float* p = (float*)d_ws;
  float* link = p;   p += (size_t)BA * NC * NC;   // 16 MB; never read-before-write
  float* mem = p;    p += (size_t)BA * NC * WSZ;  // 2 MB; t=0 read is guarded
  float* iface = p;  p += (size_t)BA * TS * IFSZ;

  hipLaunchKernelGGL(iface_kernel, dim3(BA * TS), dim3(512), 0, stream,
                     ctrl, Wif, bif, iface);
  hipLaunchKernelGGL(dnc_mega, dim3(BA), dim3(512), 0, stream,
                     iface, mem, link, out);
}